// Round 1
// 103.023 us; speedup vs baseline: 1.0021x; 1.0021x over previous
//
#include <hip/hip_runtime.h>

// SNN forward: T=128, B=8192, I=2, H=256, O=2
//  cur[t,b,h] = x[t,b,0]*W1[h,0] + x[t,b,1]*W1[h,1]
//  scan: reset = (mem>1); mem = 0.9*mem + cur - reset; spk = (mem>1)
//  out[b,o] = (mean of spk over last 10 t) dot W2[o,:]
//
// R11 = R10 + packed-FP32 math (v_pk_mul_f32 / v_pk_add_f32):
//  The kernel is VALU-issue-bound (VALUBusy 73%, ~2.7-3 cyc/instr sustained
//  issue = the m07 wall; MFMA/HBM idle). The 8-op chain step is fixed by
//  exact-numerics requirements, so the lever is instructions-per-element:
//  pair the 8 h-chains into 4 even-aligned VGPR pairs and run the 6
//  mul/add/sub ops as VOP3P packed-f32 (IEEE-identical per 32-bit half).
//  Per pair per t: 6 pk + 2x(v_cmp+v_cndmask) = 10 instrs / 2 elems
//  (was 16). Spike subtraction is expressed as pk_add(m2, spkn) with
//  spkn in {-1.0, -0.0}: a + (-1.0) is bitwise a - 1.0; the only +0/-0
//  divergence cannot flip a (>1.0) compare, so spikes/outputs match.
//  Inline asm pins the pk forms (SROA would otherwise scalarize).
//
// Kept from R10: RH=8 chains/thread, saddr-form loads (t*BATCH wave-uniform
// SGPR base + fixed lane voffset), PF=8 rotating prefetch, no VGPR clamp,
// XCD swizzle (bg=blockIdx&127, hg=blockIdx>>7: all 8 hg-sharers of one
// x-slice land on the same XCD -> one L2 fill serves all).
//
// Spike-path numerics: per-op fp32 rounding, no FMA; per-element op order
// and epilogue reduction order identical to the absmax-0.0 kernels
// (R1/R2/R4/R5/R7/R8/R9/R10). cntneg/-10.0f is IEEE-identical to cnt/10.0f.

#define T_STEPS 128
#define BATCH   8192
#define HID     256
#define TAIL    10
#define RH      8      // hidden chains per thread
#define NP      (RH/2) // packed pairs per thread
#define LB      64     // batch rows per block (= lanes per wave)
#define NWAVE   4      // waves per block; block covers NWAVE*RH = 32 h
#define HG      8      // h-groups (HID / 32)
#define NBG     (BATCH / LB)   // 128 batch groups
#define PF      8      // prefetch depth (t-steps in flight)

typedef float f32x2 __attribute__((ext_vector_type(2)));

// Packed fp32 VALU ops (gfx90a+/gfx950 VOP3P, full IEEE per 32-bit half).
// Non-volatile: scheduler may interleave the 4 pair-chains freely.
#define PK_MUL(d, a, b) asm("v_pk_mul_f32 %0, %1, %2" : "=v"(d) : "v"(a), "v"(b))
#define PK_ADD(d, a, b) asm("v_pk_add_f32 %0, %1, %2" : "=v"(d) : "v"(a), "v"(b))

__global__ __launch_bounds__(256) void snn_scan(const float* __restrict__ x,
                                                const float* __restrict__ W1,
                                                const float* __restrict__ W2,
                                                float2* __restrict__ partial) {
    const int tid   = threadIdx.x;
    const int lane  = tid & 63;
    const int wave  = tid >> 6;
    const int bg    = blockIdx.x & (NBG - 1);  // same bg -> same XCD for all hg
    const int hg    = blockIdx.x >> 7;
    const int b     = bg * LB + lane;          // batch row (lane part of addr)
    const int hbase = hg * (NWAVE * RH) + wave * RH;

    // W1 rows for my 8 h, packed as (r even, r odd) pairs.
    // Wave-uniform addresses -> scalarized, one-time.
    f32x2 w0p[NP], w1p[NP];
#pragma unroll
    for (int p = 0; p < NP; ++p) {
        w0p[p].x = W1[2 * (hbase + 2 * p)];
        w0p[p].y = W1[2 * (hbase + 2 * p + 1)];
        w1p[p].x = W1[2 * (hbase + 2 * p) + 1];
        w1p[p].y = W1[2 * (hbase + 2 * p + 1) + 1];
    }

    // Uniform-base addressing: xp + t*BATCH is wave-uniform (SGPR base,
    // SALU-stepped); + b is the fixed per-lane voffset.
    const float2* xp = (const float2*)x;

    f32x2 mem[NP], spkn[NP], cnt[NP];   // spkn, cnt hold NEGATED spikes/counts
#pragma unroll
    for (int p = 0; p < NP; ++p) {
        mem[p]  = f32x2{0.0f, 0.0f};
        spkn[p] = f32x2{0.0f, 0.0f};
        cnt[p]  = f32x2{0.0f, 0.0f};
    }

    const f32x2 k09 = {0.9f, 0.9f};

#define LOADX(t) xp[(size_t)(t) * BATCH + b]

    // Per-element op sequence identical to the scalar absmax-0.0 kernel:
    //   c   = (xa*w0) + (xc*w1)
    //   mem = ((0.9*mem) + c) + (-spk)        [== sub(add(mul,..), spk)]
    //   spk = (mem > 1)                        [stored negated]
#define STEPP(p)                                              \
    {                                                         \
        f32x2 t0, t1, cc, m1, m2;                             \
        PK_MUL(t0, xaa, w0p[p]);                              \
        PK_MUL(t1, xcc, w1p[p]);                              \
        PK_ADD(cc, t0, t1);                                   \
        PK_MUL(m1, k09, mem[p]);                              \
        PK_ADD(m2, m1, cc);                                   \
        PK_ADD(mem[p], m2, spkn[p]);                          \
        spkn[p].x = (mem[p].x > 1.0f) ? -1.0f : 0.0f;         \
        spkn[p].y = (mem[p].y > 1.0f) ? -1.0f : 0.0f;         \
    }

    // ---- warm-up: fill rotating prefetch buffer with t = 0..7 ----
    float2 buf[PF];
#pragma unroll
    for (int j = 0; j < PF; ++j) buf[j] = LOADX(j);

    // ---- main loop: t = 0..111 (14 iters), prefetch t+8 (<= 119) ----
    for (int tb = 0; tb < T_STEPS - 2 * PF; tb += PF) {
#pragma unroll
        for (int j = 0; j < PF; ++j) {
            const float2 xv = buf[j];
            buf[j] = LOADX(tb + PF + j);
            const f32x2 xaa = {xv.x, xv.x};
            const f32x2 xcc = {xv.y, xv.y};
#pragma unroll
            for (int p = 0; p < NP; ++p) STEPP(p)
        }
    }

    // ---- t = 112..119: consume buf[j], refill with t = 120..127 ----
#pragma unroll
    for (int j = 0; j < PF; ++j) {
        const float2 xv = buf[j];
        buf[j] = LOADX(T_STEPS - PF + j);
        const f32x2 xaa = {xv.x, xv.x};
        const f32x2 xcc = {xv.y, xv.y};
#pragma unroll
        for (int p = 0; p < NP; ++p) {
            STEPP(p)
            if (j >= PF - 2) PK_ADD(cnt[p], cnt[p], spkn[p]);  // t = 118, 119
        }
    }
    // ---- t = 120..127 (all counted) ----
#pragma unroll
    for (int j = 0; j < PF; ++j) {
        const float2 xv = buf[j];
        const f32x2 xaa = {xv.x, xv.x};
        const f32x2 xcc = {xv.y, xv.y};
#pragma unroll
        for (int p = 0; p < NP; ++p) {
            STEPP(p)
            PK_ADD(cnt[p], cnt[p], spkn[p]);   // integer-valued, exact in fp32
        }
    }
#undef STEPP
#undef LOADX

    // per-thread partial of out[b, :] over my 8 h (ascending h order).
    // cnt holds -count; x / -10.0f is IEEE-identical to (-x) / 10.0f.
    float p0 = 0.0f, p1 = 0.0f;
#pragma unroll
    for (int p = 0; p < NP; ++p) {
        const float a0 = cnt[p].x / -10.0f;
        p0 = __fadd_rn(p0, __fmul_rn(a0, W2[hbase + 2 * p]));
        p1 = __fadd_rn(p1, __fmul_rn(a0, W2[HID + hbase + 2 * p]));
        const float a1 = cnt[p].y / -10.0f;
        p0 = __fadd_rn(p0, __fmul_rn(a1, W2[hbase + 2 * p + 1]));
        p1 = __fadd_rn(p1, __fmul_rn(a1, W2[HID + hbase + 2 * p + 1]));
    }

    // combine the block's 4 waves (different h-chunks, same b per lane)
    __shared__ float2 red[NWAVE][LB];
    red[wave][lane] = make_float2(p0, p1);
    __syncthreads();
    if (wave == 0) {
        const float2 a0 = red[0][lane], a1 = red[1][lane];
        const float2 a2 = red[2][lane], a3 = red[3][lane];
        float2 s;
        s.x = __fadd_rn(__fadd_rn(a0.x, a1.x), __fadd_rn(a2.x, a3.x));
        s.y = __fadd_rn(__fadd_rn(a0.y, a1.y), __fadd_rn(a2.y, a3.y));
        partial[(size_t)hg * BATCH + b] = s;
    }
}

// sum the 8 h-group partials -> out[b, 0:2]
__global__ __launch_bounds__(256) void snn_reduce(const float2* __restrict__ partial,
                                                  float2* __restrict__ out) {
    const int b = blockIdx.x * 256 + threadIdx.x;   // 8192 threads
    float sx = 0.0f, sy = 0.0f;
#pragma unroll
    for (int hg = 0; hg < HG; ++hg) {
        const float2 p = partial[(size_t)hg * BATCH + b];
        sx = __fadd_rn(sx, p.x);
        sy = __fadd_rn(sy, p.y);
    }
    out[b] = make_float2(sx, sy);
}

extern "C" void kernel_launch(void* const* d_in, const int* in_sizes, int n_in,
                              void* d_out, int out_size, void* d_ws, size_t ws_size,
                              hipStream_t stream) {
    const float* x  = (const float*)d_in[0];  // (128, 8192, 2)
    const float* W1 = (const float*)d_in[1];  // (256, 2)
    const float* W2 = (const float*)d_in[2];  // (2, 256)
    float2* out     = (float2*)d_out;         // (8192, 2)
    float2* partial = (float2*)d_ws;          // (8, 8192) float2 = 512 KB scratch

    snn_scan<<<NBG * HG, 256, 0, stream>>>(x, W1, W2, partial);
    snn_reduce<<<BATCH / 256, 256, 0, stream>>>(partial, out);
}